// Round 14
// baseline (355.893 us; speedup 1.0000x reference)
//
#include <hip/hip_runtime.h>
#include <hip/hip_fp16.h>
#include <stdint.h>

#define TROWS 51712   // 512*101
#define NCITY 101
#define BATCH 512
#define EDIM  128
#define NBH   4096    // BATCH*8 heads

using half_t = _Float16;
typedef __attribute__((ext_vector_type(8))) _Float16 h8;
typedef __attribute__((ext_vector_type(4))) _Float16 h4;
typedef __attribute__((ext_vector_type(4))) float   f32x4;

typedef __attribute__((address_space(1))) const unsigned int gu32;
typedef __attribute__((address_space(3))) unsigned int lu32;
static __device__ __forceinline__ void async16(const void* g, const void* l) {
    __builtin_amdgcn_global_load_lds((gu32*)g, (lu32*)(uint32_t)(uintptr_t)l, 16, 0, 0);
}

// Quarter-XOR image swizzle (weights only): element (row, c) stored at
// c' = (c & ~31) | ((((c>>3) ^ (row>>1)) & 3) << 3) | (c & 7).
static __device__ __forceinline__ int swz_col(int c, int row) {
    return (c & ~31) | ((((c >> 3) ^ (row >> 1)) & 3) << 3) | (c & 7);
}

// ---------------- one-shot weight prep: all transposes + bias pack ----------------
__global__ __launch_bounds__(256)
void prep_kernel(const float* __restrict__ Wq, const float* __restrict__ Wk,
                 const float* __restrict__ Wv, const float* __restrict__ Wo,
                 const float* __restrict__ Wf1, const float* __restrict__ Wf2,
                 const float* __restrict__ bq, const float* __restrict__ bk,
                 const float* __restrict__ bv,
                 half_t* __restrict__ wqkv, half_t* __restrict__ wo,
                 half_t* __restrict__ wf1, half_t* __restrict__ wf2,
                 float* __restrict__ bqkv)
{
    const int which = blockIdx.y;
    const int gid = blockIdx.x * 256 + threadIdx.x;
    if (which <= 2) {
        if (gid >= 3 * 128 * 128) return;
        const float* src = (which == 0) ? Wq : (which == 1) ? Wk : Wv;
        int l = gid >> 14, r = gid & 16383, k = r >> 7, n = r & 127;
        wqkv[(size_t)l * 49152 + which * 16384 + n * 128 + swz_col(k, n)] = (half_t)src[gid];
    } else if (which == 3) {
        if (gid >= 3 * 128 * 128) return;
        int l = gid >> 14, r = gid & 16383, k = r >> 7, n = r & 127;
        wo[(size_t)l * 16384 + n * 128 + swz_col(k, n)] = (half_t)Wo[gid];
    } else if (which == 4) {
        // wf1 image: [l][j(8)][kc(4)][n(64)][h'(32)]
        if (gid >= 3 * 65536) return;
        int l = gid >> 16, u = gid & 65535;
        int j = u >> 13, kc = (u >> 11) & 3, n = (u >> 5) & 63, hp = u & 31;
        int k = kc * 32 + ((((hp >> 3) ^ (n >> 1)) & 3) << 3) + (hp & 7);
        wf1[(size_t)l * 65536 + u] = (half_t)Wf1[(size_t)(l * 128 + k) * 512 + j * 64 + n];
    } else if (which == 5) {
        // wf2 image: [l][j(8)][kc2(2)][n(128)][h'(32)]
        if (gid >= 3 * 65536) return;
        int l = gid >> 16, u = gid & 65535;
        int j = u >> 13, kc = (u >> 12) & 1, n = (u >> 5) & 127, hp = u & 31;
        int kh = j * 64 + kc * 32 + ((((hp >> 3) ^ (n >> 1)) & 3) << 3) + (hp & 7);
        wf2[(size_t)l * 65536 + u] = (half_t)Wf2[(size_t)(l * 512 + kh) * 128 + n];
    } else {
        if (gid >= 3 * 384) return;
        int l = gid / 384, c = gid - l * 384;
        float v = (c < 128) ? bq[l * 128 + c]
                : (c < 256) ? bk[l * 128 + c - 128]
                            : bv[l * 128 + c - 256];
        bqkv[gid] = v;
    }
}

// ---------------- embedding (plain xh) ----------------
__global__ __launch_bounds__(256)
void embed_kernel(const float* __restrict__ s, const int* __restrict__ d,
                  const float* __restrict__ e_w, const float* __restrict__ e_b,
                  const float* __restrict__ ep_w, const float* __restrict__ ep_b,
                  half_t* __restrict__ xh)
{
    int gid = blockIdx.x * 256 + threadIdx.x;      // over TROWS*128
    int row = gid >> 7;
    int c   = gid & 127;
    int b = row / NCITY;
    int n = row - b * NCITY;
    const float* sp = s + ((size_t)b * NCITY + n) * 2;
    float v;
    if (n == 0) {
        v = sp[0] * ep_w[c] + sp[1] * ep_w[128 + c] + ep_b[c];
    } else {
        float dv = (float)d[b * NCITY + n];
        v = sp[0] * e_w[c] + sp[1] * e_w[128 + c] + dv * e_w[256 + c] + e_b[c];
    }
    xh[gid] = (half_t)v;
}

// ---------------- fused [BN2-prev] + QKV + attention + O-proj + residual + BN1 stats
// One block per batch element, 512 threads, 8 waves = 1 wave per head.
// 80 KB LDS -> 2 blocks/CU. Register-lean EVERYWHERE for the (512,4)
// 64-arch-VGPR split: phase 2 = 3 sequential passes (one 16-reg weight set
// live at a time, r13); phase 3 re-reads kf from wave-private sK per tile
// (r12) so only vt[4] (16 regs) is hoisted.
//   Region A (28,672 B): sX (phases 1-2) -> sQ overlay (post-phase-2).
//   Region B (53,248 B): sK (live through ph3) | sV; sO [104][128]
//                        (XOR-8 granule swizzle) overlays sV after vt hoist.
__global__ __launch_bounds__(512, 4)
void layer_attn(const half_t* __restrict__ xsrc, const float* __restrict__ stats0,
                const float* __restrict__ g0, const float* __restrict__ be0,
                const half_t* __restrict__ wqkv, const float* __restrict__ bqkv,
                const half_t* __restrict__ wo, const float* __restrict__ bo,
                half_t* __restrict__ y16, float* __restrict__ stats)
{
    __shared__ alignas(16) half_t regA[14336];   // 28,672 B
    __shared__ alignas(16) half_t regB[26624];   // 53,248 B
    half_t* sX = regA;                 // [4][112*32]
    half_t* sQ = regA;                 // [8][112*16]  (overlay, post-phase-2)
    half_t* sK = regB;                 // [8][104*16]  (live through phase 3)
    half_t* sV = regB + 13312;         // [8][104*16]
    half_t* sO = regB + 13312;         // [104][128]   (overlay after vt hoist)
    float* sBN2 = (float*)regB;        // 1 KB table (phase 1 only)

    const int b   = blockIdx.x;
    const int tid = threadIdx.x;
    const int wave = tid >> 6, lane = tid & 63;
    const int quad = lane >> 4, l16 = lane & 15;
    const float invN = 1.0f / (float)TROWS;

    // ---- phase 1: BN2 table (if prev layer), then stage x' tile
    if (stats0) {
        if (tid < 128) {
            float mean = stats0[tid] * invN;
            float var  = stats0[128 + tid] * invN - mean * mean;
            float scl  = g0[tid] * rsqrtf(var + 1e-5f);
            sBN2[tid]       = scl;
            sBN2[128 + tid] = be0[tid] - mean * scl;
        }
        __syncthreads();
    }
    if (tid < 448) {
        int row = tid >> 2, q = tid & 3;
        int qs = ((q ^ (row >> 1)) & 3) << 3;
        h8 out[4];
        if (row < NCITY) {
            const half_t* src = xsrc + ((size_t)b * NCITY + row) * 128 + q * 8;
            #pragma unroll
            for (int kc = 0; kc < 4; ++kc) {
                h8 v = *(const h8*)(src + kc * 32);
                if (stats0) {
                    #pragma unroll
                    for (int r = 0; r < 8; ++r) {
                        int c = kc * 32 + q * 8 + r;
                        v[r] = (half_t)((float)v[r] * sBN2[c] + sBN2[128 + c]);
                    }
                }
                out[kc] = v;
            }
        } else {
            h8 z = {};
            out[0] = z; out[1] = z; out[2] = z; out[3] = z;
        }
        #pragma unroll
        for (int kc = 0; kc < 4; ++kc)
            *(h8*)(&sX[kc * 3584 + row * 32 + qs]) = out[kc];
    }
    __syncthreads();

    // ---- phase 2: per-wave QKV for head `wave`, 3 register-lean passes
    const int hn  = wave * 16 + l16;         // output column 0..127
    const int nsw = (hn >> 1) & 3;
    half_t* dstK = sK + wave * 1664;
    half_t* dstV = sV + wave * 1664;

    // K pass
    {
        h8 bw[4];
        const half_t* wrow = wqkv + 16384 + (size_t)hn * 128;
        #pragma unroll
        for (int kc = 0; kc < 4; ++kc)
            bw[kc] = *(const h8*)(wrow + kc * 32 + (((quad ^ nsw) & 3) << 3));
        float bb = bqkv[128 + hn];
        #pragma unroll
        for (int mi = 0; mi < 7; ++mi) {
            f32x4 a = {};
            #pragma unroll
            for (int kc = 0; kc < 4; ++kc) {
                int r = mi * 16 + l16;
                h8 af = *(const h8*)(&sX[kc * 3584 + r * 32 + (((quad ^ (r >> 1)) & 3) << 3)]);
                a = __builtin_amdgcn_mfma_f32_16x16x32_f16(af, bw[kc], a, 0, 0, 0);
            }
            #pragma unroll
            for (int r = 0; r < 4; ++r) {
                int tok = mi * 16 + quad * 4 + r;
                if (tok < 104)
                    dstK[tok * 16 + (l16 ^ (((tok >> 2) & 1) << 3))] = (half_t)(a[r] + bb);
            }
        }
    }
    __builtin_amdgcn_sched_barrier(0);
    // V pass
    {
        h8 bw[4];
        const half_t* wrow = wqkv + 2 * 16384 + (size_t)hn * 128;
        #pragma unroll
        for (int kc = 0; kc < 4; ++kc)
            bw[kc] = *(const h8*)(wrow + kc * 32 + (((quad ^ nsw) & 3) << 3));
        float bb = bqkv[256 + hn];
        #pragma unroll
        for (int mi = 0; mi < 7; ++mi) {
            f32x4 a = {};
            #pragma unroll
            for (int kc = 0; kc < 4; ++kc) {
                int r = mi * 16 + l16;
                h8 af = *(const h8*)(&sX[kc * 3584 + r * 32 + (((quad ^ (r >> 1)) & 3) << 3)]);
                a = __builtin_amdgcn_mfma_f32_16x16x32_f16(af, bw[kc], a, 0, 0, 0);
            }
            #pragma unroll
            for (int r = 0; r < 4; ++r) {
                int tok = mi * 16 + quad * 4 + r;
                if (tok < 104)
                    dstV[tok * 16 + (l16 ^ (((tok >> 2) & 1) << 3))] = (half_t)(a[r] + bb);
            }
        }
    }
    __builtin_amdgcn_sched_barrier(0);
    // Q pass -> packed regs (sQ overlay not writable until barrier)
    h4 qh[7];
    {
        h8 bw[4];
        const half_t* wrow = wqkv + (size_t)hn * 128;
        #pragma unroll
        for (int kc = 0; kc < 4; ++kc)
            bw[kc] = *(const h8*)(wrow + kc * 32 + (((quad ^ nsw) & 3) << 3));
        float bb = bqkv[hn];
        #pragma unroll
        for (int mi = 0; mi < 7; ++mi) {
            f32x4 a = {};
            #pragma unroll
            for (int kc = 0; kc < 4; ++kc) {
                int r = mi * 16 + l16;
                h8 af = *(const h8*)(&sX[kc * 3584 + r * 32 + (((quad ^ (r >> 1)) & 3) << 3)]);
                a = __builtin_amdgcn_mfma_f32_16x16x32_f16(af, bw[kc], a, 0, 0, 0);
            }
            #pragma unroll
            for (int r = 0; r < 4; ++r)
                qh[mi][r] = (half_t)(a[r] + bb);
        }
    }
    __syncthreads();   // all sX reads + K/V writes done -> sQ overlay safe, K/V visible

    // write Q into region A (wave-private chunk of old sX)
    {
        half_t* dstQ = sQ + wave * 1792;
        #pragma unroll
        for (int mi = 0; mi < 7; ++mi)
            #pragma unroll
            for (int r = 0; r < 4; ++r) {
                int tok = mi * 16 + quad * 4 + r;
                int dsw = l16 ^ (((tok >> 2) & 1) << 3);
                dstQ[tok * 16 + dsw] = qh[mi][r];
            }
    }
    const half_t* qb = sQ + wave * 1792;
    const half_t* kb = sK + wave * 1664;
    const half_t* vb = sV + wave * 1664;
    const int kflip = (l16 >> 2) & 1;

    // hoist V fragments only (16 VGPRs); kf re-read per tile in phase 3
    h8 vt[4];
    #pragma unroll
    for (int p = 0; p < 4; ++p)
        #pragma unroll
        for (int jj = 0; jj < 8; ++jj) {
            int tok = p * 32 + quad * 8 + jj;
            int tokc = tok < 104 ? tok : 103;   // clamped; P=0 for tok>=101
            vt[p][jj] = vb[tokc * 16 + (l16 ^ (((jj >> 2) & 1) << 3))];
        }
    __syncthreads();   // all V reads + Q writes done -> sO (over sV) safe

    // ---- phase 3: attention (per-wave private; K re-read from LDS per tile)
    const int s0 = (((quad & 1) * 2)    ) * 16 + l16;
    const int s1 = (((quad & 1) * 2) + 1) * 16 + l16;
    const bool hi2 = (quad >> 1) != 0;
    const int ocol = hn;                       // this wave's output column

    for (int it = 0; it < 7; ++it) {
        h8 qf = {};
        if (quad < 2)
            qf = *(const h8*)(qb + (it * 16 + l16) * 16 + ((quad ^ kflip) << 3));

        f32x4 S[7];
        #pragma unroll
        for (int jt = 0; jt < 7; ++jt) {
            h8 kf = {};
            if (quad < 2) {
                int rowk = jt * 16 + l16;
                rowk = rowk < 104 ? rowk : 103;   // clamped; masked downstream
                kf = *(const h8*)(kb + rowk * 16 + ((quad ^ kflip) << 3));
            }
            f32x4 a = {};
            a = __builtin_amdgcn_mfma_f32_16x16x32_f16(kf, qf, a, 0, 0, 0);
            S[jt] = a;
        }
        float m = -1e30f;
        #pragma unroll
        for (int jt = 0; jt < 7; ++jt)
            #pragma unroll
            for (int r = 0; r < 4; ++r) {
                int jg = jt * 16 + quad * 4 + r;
                float sv = (jg < NCITY) ? S[jt][r] * 0.25f : -1e30f;
                S[jt][r] = sv;
                m = fmaxf(m, sv);
            }
        m = fmaxf(m, __shfl_xor(m, 16));
        m = fmaxf(m, __shfl_xor(m, 32));
        float sum = 0.0f;
        #pragma unroll
        for (int jt = 0; jt < 7; ++jt)
            #pragma unroll
            for (int r = 0; r < 4; ++r) {
                float e = __expf(S[jt][r] - m);
                S[jt][r] = e;
                sum += e;
            }
        sum += __shfl_xor(sum, 16);
        sum += __shfl_xor(sum, 32);
        float inv = 1.0f / sum;
        #pragma unroll
        for (int jt = 0; jt < 7; ++jt)
            #pragma unroll
            for (int r = 0; r < 4; ++r) S[jt][r] *= inv;

        f32x4 O = {};
        #pragma unroll
        for (int p = 0; p < 4; ++p) {
            float pj[8];
            #pragma unroll
            for (int r = 0; r < 4; ++r) {
                float a0 = __shfl(S[2 * p][r],     s0);
                float b0 = __shfl(S[2 * p + 1][r], s0);
                float a1 = __shfl(S[2 * p][r],     s1);
                float b1 = __shfl(S[2 * p + 1][r], s1);
                pj[r]     = hi2 ? b0 : a0;
                pj[4 + r] = hi2 ? b1 : a1;
            }
            h8 ph;
            #pragma unroll
            for (int jj = 0; jj < 8; ++jj)
                ph[jj] = (half_t)pj[jj];
            O = __builtin_amdgcn_mfma_f32_16x16x32_f16(ph, vt[p], O, 0, 0, 0);
        }
        // O -> sO[104][128], granule swizzle g' = g ^ (q&7) -> conflict-free
        #pragma unroll
        for (int r = 0; r < 4; ++r) {
            int q = it * 16 + quad * 4 + r;
            if (q < 104) {
                int g = (ocol >> 3) ^ (q & 7);
                sO[q * 128 + g * 8 + (ocol & 7)] = (half_t)O[r];
            }
        }
    }
    __syncthreads();

    // ---- phase 4: O-proj (wave w owns cols w*16..+15), residual(+BN2), BN1 stats
    h8 bfr2[4];
    {
        const half_t* wrow = wo + (size_t)ocol * 128;
        const int nsw2 = (ocol >> 1) & 3;
        #pragma unroll
        for (int kc = 0; kc < 4; ++kc)
            bfr2[kc] = *(const h8*)(wrow + kc * 32 + (((quad ^ nsw2) & 3) << 3));
    }
    f32x4 acc[7];
    #pragma unroll
    for (int mi = 0; mi < 7; ++mi) {
        acc[mi] = (f32x4){};
        int row = mi * 16 + l16;
        int rc = row < 104 ? row : 103;   // rows>=104 garbage -> masked at store
        #pragma unroll
        for (int kc = 0; kc < 4; ++kc) {
            int g = (kc * 4 + quad) ^ (rc & 7);
            h8 af = *(const h8*)(&sO[rc * 128 + g * 8]);
            acc[mi] = __builtin_amdgcn_mfma_f32_16x16x32_f16(af, bfr2[kc], acc[mi], 0, 0, 0);
        }
    }
    float sclo = 1.0f, shfo = 0.0f;
    if (stats0) {
        float mean = stats0[ocol] * invN;
        float var  = stats0[128 + ocol] * invN - mean * mean;
        sclo = g0[ocol] * rsqrtf(var + 1e-5f);
        shfo = be0[ocol] - mean * sclo;
    }
    float bvv = bo[ocol];
    float s = 0.0f, ss = 0.0f;
    #pragma unroll
    for (int mi = 0; mi < 7; ++mi) {
        #pragma unroll
        for (int r = 0; r < 4; ++r) {
            int q = mi * 16 + quad * 4 + r;
            if (q < NCITY) {
                size_t grow = (size_t)b * NCITY + q;
                float xv = (float)xsrc[grow * 128 + ocol] * sclo + shfo;
                float o = acc[mi][r] + bvv + xv;
                y16[grow * 128 + ocol] = (half_t)o;
                s += o; ss += o * o;
            }
        }
    }
    s  += __shfl_xor(s, 16);  s  += __shfl_xor(s, 32);
    ss += __shfl_xor(ss, 16); ss += __shfl_xor(ss, 32);
    if (quad == 0) {
        atomicAdd(&stats[ocol], s);
        atomicAdd(&stats[128 + ocol], ss);
    }
}

// ---------------- fused BN1 + FF1(ReLU) + FF2 ----------------
// 512 threads / 8 waves, 80 KB LDS -> 2 blocks/CU.
// Weights reg-staged: next round's loads issued under compute.
// Epilogue residual x' read back from sX (LDS) -- no y16 re-read.
__global__ __launch_bounds__(512, 4)
void ff_fused(half_t* __restrict__ y16, const float* __restrict__ st1,
              const float* __restrict__ g1, const float* __restrict__ be1,
              const half_t* __restrict__ w1, const half_t* __restrict__ w2,
              const float* __restrict__ bf1, const float* __restrict__ bf2,
              float* __restrict__ stats)
{
    __shared__ alignas(16) half_t sX[4][128 * 32];   // 32 KB  x' tile
    __shared__ alignas(16) half_t sW1f[8192];        // 16 KB  wf1 chunk image (flat)
    __shared__ alignas(16) half_t sW2f[8192];        // 16 KB  wf2 chunk image (flat)
    __shared__ alignas(16) half_t sH[2][128 * 32];   // 16 KB  relu chunk

    const int tid  = threadIdx.x;
    const int wave = tid >> 6, lane = tid & 63;
    const int quad = lane >> 4, l16 = lane & 15;
    const int m0 = blockIdx.x * 128;
    const int wr = wave >> 1;          // 0..3: 32-row group
    const int wc = wave & 1;           // col group

    const float invN = 1.0f / (float)TROWS;
    const int so = wave * 512 + lane * 8;    // identity global<->LDS offset

    // prologue: round-0 weight regs
    h8 rw1a = *(const h8*)(w1 + so);
    h8 rw1b = *(const h8*)(w1 + so + 4096);
    h8 rw2a = *(const h8*)(w2 + so);
    h8 rw2b = *(const h8*)(w2 + so + 4096);

    // BN1 scale/shift table (1 KB, overlaid in sW1f; dead after sX stage)
    float* sBN = (float*)&sW1f[0];
    if (tid < 128) {
        float mean = st1[tid] * invN;
        float var  = st1[128 + tid] * invN - mean * mean;
        float scl  = g1[tid] * rsqrtf(var + 1e-5f);
        sBN[tid]       = scl;
        sBN[128 + tid] = be1[tid] - mean * scl;
    }
    __syncthreads();

    // stage x' = BN1(y16) -> sX (swizzled)
    {
        const int row = tid >> 2;            // 0..127
        const int q   = tid & 3;
        const int qs  = ((q ^ (row >> 1)) & 3) << 3;
        const half_t* src = y16 + (size_t)(m0 + row) * 128 + q * 8;
        #pragma unroll
        for (int kc = 0; kc < 4; ++kc) {
            h8 v = *(const h8*)(src + kc * 32);
            h8 xv;
            #pragma unroll
            for (int r = 0; r < 8; ++r) {
                int c = kc * 32 + q * 8 + r;
                xv[r] = (half_t)((float)v[r] * sBN[c] + sBN[128 + c]);
            }
            *(h8*)(&sX[kc][row * 32 + qs]) = xv;
        }
    }

    f32x4 acc2[2][4] = {};

    for (int j = 0; j < 8; ++j) {
        // b1: FF2(j-1) done reading sW/sH; sX/sBN writes visible (j=0)
        asm volatile("s_waitcnt lgkmcnt(0)" ::: "memory");
        __builtin_amdgcn_s_barrier();
        __builtin_amdgcn_sched_barrier(0);
        // write W(j) from regs (compiler inserts the per-thread vmcnt waits)
        *(h8*)(&sW1f[so])        = rw1a;
        *(h8*)(&sW1f[so + 4096]) = rw1b;
        *(h8*)(&sW2f[so])        = rw2a;
        *(h8*)(&sW2f[so + 4096]) = rw2b;
        asm volatile("s_waitcnt lgkmcnt(0)" ::: "memory");
        __builtin_amdgcn_s_barrier();
        __builtin_amdgcn_sched_barrier(0);
        if (j < 7) {   // issue next round's loads; they fly under FF1+FF2
            const half_t* w1n = w1 + (size_t)(j + 1) * 8192;
            const half_t* w2n = w2 + (size_t)(j + 1) * 8192;
            rw1a = *(const h8*)(w1n + so);
            rw1b = *(const h8*)(w1n + so + 4096);
            rw2a = *(const h8*)(w2n + so);
            rw2b = *(const h8*)(w2n + so + 4096);
        }

        // FF1: wave tile 32x32 of 128x64 chunk
        f32x4 acc1[2][2] = {};
        #pragma unroll
        for (int kc = 0; kc < 4; ++kc) {
            h8 af[2], bf[2];
            #pragma unroll
            for (int mi = 0; mi < 2; ++mi) {
                int r = wr * 32 + mi * 16 + l16;
                af[mi] = *(const h8*)(&sX[kc][r * 32 + (((quad ^ (r >> 1)) & 3) << 3)]);
            }
            #pragma unroll
            for (int ni = 0; ni < 2; ++ni) {
                int n = wc * 32 + ni * 16 + l16;
                bf[ni] = *(const h8*)(&sW1f[kc * 2048 + n * 32 + (((quad ^ (n >> 1)) & 3) << 3)]);
            }
            #pragma unroll
            for (int mi = 0; mi < 2; ++mi)
            #pragma unroll
            for (int ni = 0; ni < 2; ++ni)
                acc1[mi][ni] = __builtin_amdgcn_mfma_f32_16x16x32_f16(af[mi], bf[ni], acc1[mi][ni], 0, 0, 0);
        }
        // bias + ReLU -> sH (swizzled scalar writes)
        #pragma unroll
        for (int ni = 0; ni < 2; ++ni) {
            int c = wc * 32 + ni * 16 + l16;       // 0..63
            float bvv = bf1[j * 64 + c];
            int kc2 = c >> 5, c5 = c & 31;
            #pragma unroll
            for (int mi = 0; mi < 2; ++mi)
            #pragma unroll
            for (int r = 0; r < 4; ++r) {
                int row = wr * 32 + mi * 16 + quad * 4 + r;
                float v = acc1[mi][ni][r] + bvv;
                v = v > 0.0f ? v : 0.0f;
                int hsw = (c5 & 7) | ((((c5 >> 3) ^ (row >> 1)) & 3) << 3);
                sH[kc2][row * 32 + hsw] = (half_t)v;
            }
        }
        asm volatile("s_waitcnt lgkmcnt(0)" ::: "memory");
        __builtin_amdgcn_s_barrier();
        __builtin_amdgcn_sched_barrier(0);

        // FF2 partial: wave tile 32x64, K-slice 64
        #pragma unroll
        for (int kc = 0; kc < 2; ++kc) {
            h8 af[2], bf[4];
            #pragma unroll
            for (int mi = 0; mi < 2; ++mi) {
                int r = wr * 32 + mi * 16 + l16;
                af[mi] = *(const h8*)(&sH[kc][r * 32 + (((quad ^ (r >> 1)) & 3) << 3)]);
            }
            #pragma unroll
            for (int ni = 0; ni < 4; ++ni) {
                int n = wc * 64 + ni * 16 + l16;
                bf[ni] = *(const h8*)(&sW2f[kc * 4096 + n * 32 + (((quad ^ (n >> 1)) & 3) << 3)]);
            }
            #pragma unroll
            for (int mi = 0; mi < 2; ++mi)
            #pragma unroll
            for (int ni = 0; ni < 4; ++ni)
                acc2[mi][ni] = __builtin_amdgcn_mfma_f32_16x16x32_f16(af[mi], bf[ni], acc2[mi][ni], 0, 0, 0);
        }
    }

    // epilogue: y2 = acc2 + bf2 + x' (x' read from sX), BN2 stats
    __syncthreads();                       // sH reads done -> reuse as reduction scratch
    float* red = (float*)&sH[0][0];        // [2][512] floats (s, ss)

    #pragma unroll
    for (int ni = 0; ni < 4; ++ni) {
        int col = wc * 64 + ni * 16 + l16;
        float bvv = bf2[col];
        int kc = col >> 5, c5 = col & 31;
        float s = 0.0f, ss = 0.0f;
        #pragma unroll
        for (int mi = 0; mi < 2; ++mi) {
            #pragma unroll
            for (int r = 0; r < 4; ++r) {
                int rowl = wr * 32 + mi * 16 + quad * 4 + r;
                int hsw = (c5 & 7) | ((((c5 >> 3) ^ (rowl >> 1)) & 3) << 3);
                float xv = (float)sX[kc][rowl * 32 + hsw];
                float o = acc2[mi][ni][r] + bvv + xv;
                y16[(size_t)(m0 + rowl) * 128 + col] = (half_t)o;
                s += o; ss += o * o;
            }
        }
        s  += __shfl_xor(s, 16);  s  += __shfl_xor(s, 32);
        ss += __shfl_xor(ss, 16); ss += __shfl_xor(ss, 32);
        if (quad == 0) {
            red[wave * 64 + ni * 16 + l16]       = s;
            red[512 + wave * 64 + ni * 16 + l16] = ss;
        }
    }
    __syncthreads();
    if (tid < 256) {
        int a   = tid >> 7;          // 0 = s, 1 = ss
        int col = tid & 127;
        int wcc = col >> 6, nii = (col >> 4) & 3, lx = col & 15;
        float t = 0.0f;
        #pragma unroll
        for (int w = 0; w < 4; ++w)
            t += red[a * 512 + (w * 2 + wcc) * 64 + nii * 16 + lx];
        atomicAdd(&stats[a * 128 + col], t);
    }
}

// ---------------- BatchNorm apply (final layer only: fp32 out) ----------------
__global__ __launch_bounds__(256)
void bn_apply(const h8* __restrict__ y, const float* __restrict__ stats,
              const float* __restrict__ g, const float* __restrict__ be,
              float* __restrict__ dst32)
{
    __shared__ float sh[256];
    const int tid = threadIdx.x;
    if (tid < 128) {
        const float invN = 1.0f / (float)TROWS;
        float mean = stats[tid] * invN;
        float var  = stats[128 + tid] * invN - mean * mean;
        float inv  = rsqrtf(var + 1e-5f);
        float scl  = g[tid] * inv;
        sh[tid]       = scl;
        sh[128 + tid] = be[tid] - mean * scl;
    }
    __syncthreads();

    int gid = blockIdx.x * 256 + tid;   // over TROWS*16 (8 ch each)
    int c = (gid & 15) * 8;
    h8 v = y[gid];
    float o[8];
    #pragma unroll
    for (int r = 0; r < 8; ++r)
        o[r] = (float)v[r] * sh[c + r] + sh[128 + c + r];
    f32x4 lo = { o[0], o[1], o[2], o[3] };
    f32x4 hi = { o[4], o[5], o[6], o[7] };
    ((f32x4*)dst32)[gid * 2]     = lo;
    ((f32x4*)dst32)[gid * 2 + 1] = hi;
}

// ---------------- launch ----------------
extern "C" void kernel_launch(void* const* d_in, const int* in_sizes, int n_in,
                              void* d_out, int out_size, void* d_ws, size_t ws_size,
                              hipStream_t stream)
{
    const float* s    = (const float*)d_in[0];
    const int*   dd   = (const int*)d_in[1];
    const float* e_w  = (const float*)d_in[2];
    const float* e_b  = (const float*)d_in[3];
    const float* ep_w = (const float*)d_in[4];
    const float* ep_b = (const float*)d_in[5];
    const float* Wq   = (const float*)d_in[6];
    const float* bq   = (const float*)d_in[7];
    const float* Wk   = (const float*)d_in[8];
    const float* bk   = (const float*)d_in[9];
    const float* Wv   = (const float*)d_in[10];
    const float* bv   = (const float*)d_in[11];
    const float* Wo   = (const float*)d_in[12];
    const float* bo   = (const float*)d_in[13];
    const float* Wf1  = (const float*)d_in[14];
    const float* bf1  = (const float*)d_in[15];
    const float* Wf2  = (const float*)d_in[16];
    const float* bf2  = (const float*)d_in[17];
    const float* g1   = (const float*)d_in[18];
    const float* be1  = (const float*)d_in[19];
    const float* g2   = (const float*)d_in[20];
    const float* be2  = (const float*)d_in[21];

    char* ws = (char*)d_ws;
    size_t off = 0;
    auto alloc = [&](size_t bytes) -> void* {
        void* p = ws + off;
        off += (bytes + 255) & ~(size_t)255;
        return p;
    };
    half_t* y16   = (half_t*)alloc((size_t)TROWS * 128 * 2);
    half_t* xh    = (half_t*)alloc((size_t)TROWS * 128 * 2);
    half_t* wqkv  = (half_t*)alloc((size_t)3 * 384 * 128 * 2);
    half_t* wo    = (half_t*)alloc((size_t)3 * 128 * 128 * 2);
    half_t* wf1   = (half_t*)alloc((size_t)3 * 512 * 128 * 2);
    half_t* wf2   = (half_t*)alloc((size_t)3 * 128 * 512 * 2);
    float*  bqkv  = (float*) alloc((size_t)3 * 384 * 4);
    float*  stats = (float*) alloc(6 * 256 * 4);

    dim3 blk(256);

    hipMemsetAsync(stats, 0, 6 * 256 * 4, stream);

    prep_kernel<<<dim3(768, 7), blk, 0, stream>>>(Wq, Wk, Wv, Wo, Wf1, Wf2, bq, bk, bv,
                                                  wqkv, wo, wf1, wf2, bqkv);

    embed_kernel<<<dim3(TROWS * 128 / 256), blk, 0, stream>>>(s, dd, e_w, e_b, ep_w, ep_b, xh);

    for (int l = 0; l < 3; ++l) {
        float* st1 = stats + (size_t)(l * 2) * 256;
        float* st2 = stats + (size_t)(l * 2 + 1) * 256;
        const float* st0 = (l == 0) ? nullptr : stats + (size_t)((l - 1) * 2 + 1) * 256;
        const half_t* xsrc = (l == 0) ? xh : y16;
        // [BN2 prev] + QKV + attention + O-proj + residual + BN1 stats -> y16
        layer_attn<<<dim3(BATCH), dim3(512), 0, stream>>>(xsrc, st0,
                                                          g2 + (l ? (l - 1) * 128 : 0),
                                                          be2 + (l ? (l - 1) * 128 : 0),
                                                          wqkv + (size_t)l * 49152,
                                                          bqkv + l * 384,
                                                          wo + (size_t)l * 16384,
                                                          bo + l * 128, y16, st1);
        // fused BN1-apply + FF1 + FF2 + residual + BN2 stats (in-place y16)
        ff_fused<<<dim3(404), dim3(512), 0, stream>>>(y16, st1, g1 + l * 128, be1 + l * 128,
                                                      wf1 + (size_t)l * 65536, wf2 + (size_t)l * 65536,
                                                      bf1 + l * 512, bf2 + l * 128, st2);
    }
    // final BN2 apply -> fp32 output
    bn_apply<<<dim3(TROWS * 16 / 256), blk, 0, stream>>>((const h8*)y16, stats + 5 * 256,
                                                         g2 + 2 * 128, be2 + 2 * 128,
                                                         (float*)d_out);
}

// Round 15
// 333.028 us; speedup vs baseline: 1.0687x; 1.0687x over previous
//
#include <hip/hip_runtime.h>
#include <hip/hip_fp16.h>
#include <stdint.h>

#define TROWS 51712   // 512*101
#define NCITY 101
#define BATCH 512
#define EDIM  128
#define NBH   4096    // BATCH*8 heads

using half_t = _Float16;
typedef __attribute__((ext_vector_type(8))) _Float16 h8;
typedef __attribute__((ext_vector_type(4))) _Float16 h4;
typedef __attribute__((ext_vector_type(2))) _Float16 h2;
typedef __attribute__((ext_vector_type(4))) float   f32x4;
typedef __attribute__((ext_vector_type(4))) unsigned int u32x4;

typedef __attribute__((address_space(1))) const unsigned int gu32;
typedef __attribute__((address_space(3))) unsigned int lu32;
static __device__ __forceinline__ void async16(const void* g, const void* l) {
    __builtin_amdgcn_global_load_lds((gu32*)g, (lu32*)(uint32_t)(uintptr_t)l, 16, 0, 0);
}

// Quarter-XOR image swizzle (weights only): element (row, c) stored at
// c' = (c & ~31) | ((((c>>3) ^ (row>>1)) & 3) << 3) | (c & 7).
static __device__ __forceinline__ int swz_col(int c, int row) {
    return (c & ~31) | ((((c >> 3) ^ (row >> 1)) & 3) << 3) | (c & 7);
}

// ---------------- one-shot weight prep: all transposes + bias pack ----------------
__global__ __launch_bounds__(256)
void prep_kernel(const float* __restrict__ Wq, const float* __restrict__ Wk,
                 const float* __restrict__ Wv, const float* __restrict__ Wo,
                 const float* __restrict__ Wf1, const float* __restrict__ Wf2,
                 const float* __restrict__ bq, const float* __restrict__ bk,
                 const float* __restrict__ bv,
                 half_t* __restrict__ wqkv, half_t* __restrict__ wo,
                 half_t* __restrict__ wf1, half_t* __restrict__ wf2,
                 float* __restrict__ bqkv)
{
    const int which = blockIdx.y;
    const int gid = blockIdx.x * 256 + threadIdx.x;
    if (which <= 2) {
        if (gid >= 3 * 128 * 128) return;
        const float* src = (which == 0) ? Wq : (which == 1) ? Wk : Wv;
        int l = gid >> 14, r = gid & 16383, k = r >> 7, n = r & 127;
        wqkv[(size_t)l * 49152 + which * 16384 + n * 128 + swz_col(k, n)] = (half_t)src[gid];
    } else if (which == 3) {
        if (gid >= 3 * 128 * 128) return;
        int l = gid >> 14, r = gid & 16383, k = r >> 7, n = r & 127;
        wo[(size_t)l * 16384 + n * 128 + swz_col(k, n)] = (half_t)Wo[gid];
    } else if (which == 4) {
        // wf1 image: [l][j(8)][kc(4)][n(64)][h'(32)]
        if (gid >= 3 * 65536) return;
        int l = gid >> 16, u = gid & 65535;
        int j = u >> 13, kc = (u >> 11) & 3, n = (u >> 5) & 63, hp = u & 31;
        int k = kc * 32 + ((((hp >> 3) ^ (n >> 1)) & 3) << 3) + (hp & 7);
        wf1[(size_t)l * 65536 + u] = (half_t)Wf1[(size_t)(l * 128 + k) * 512 + j * 64 + n];
    } else if (which == 5) {
        // wf2 image: [l][j(8)][kc2(2)][n(128)][h'(32)]
        if (gid >= 3 * 65536) return;
        int l = gid >> 16, u = gid & 65535;
        int j = u >> 13, kc = (u >> 12) & 1, n = (u >> 5) & 127, hp = u & 31;
        int kh = j * 64 + kc * 32 + ((((hp >> 3) ^ (n >> 1)) & 3) << 3) + (hp & 7);
        wf2[(size_t)l * 65536 + u] = (half_t)Wf2[(size_t)(l * 512 + kh) * 128 + n];
    } else {
        if (gid >= 3 * 384) return;
        int l = gid / 384, c = gid - l * 384;
        float v = (c < 128) ? bq[l * 128 + c]
                : (c < 256) ? bk[l * 128 + c - 128]
                            : bv[l * 128 + c - 256];
        bqkv[gid] = v;
    }
}

// ---------------- embedding (plain xh) ----------------
__global__ __launch_bounds__(256)
void embed_kernel(const float* __restrict__ s, const int* __restrict__ d,
                  const float* __restrict__ e_w, const float* __restrict__ e_b,
                  const float* __restrict__ ep_w, const float* __restrict__ ep_b,
                  half_t* __restrict__ xh)
{
    int gid = blockIdx.x * 256 + threadIdx.x;      // over TROWS*128
    int row = gid >> 7;
    int c   = gid & 127;
    int b = row / NCITY;
    int n = row - b * NCITY;
    const float* sp = s + ((size_t)b * NCITY + n) * 2;
    float v;
    if (n == 0) {
        v = sp[0] * ep_w[c] + sp[1] * ep_w[128 + c] + ep_b[c];
    } else {
        float dv = (float)d[b * NCITY + n];
        v = sp[0] * e_w[c] + sp[1] * e_w[128 + c] + dv * e_w[256 + c] + e_b[c];
    }
    xh[gid] = (half_t)v;
}

// ---------------- fused [BN2-prev] + QKV + attention + O-proj + residual + BN1 stats
// One block per batch element, 512 threads, 8 waves = 1 wave per head.
// 80 KB LDS -> 2 blocks/CU (register-feasibility ceiling: 3 blocks/CU would
// need <=85 regs/wave; the algorithm needs ~100). Phase 2 = 3 lean passes.
// Phase 3 kf re-read per tile; P-broadcast uses PACKED f16 shuffles
// (cvt_pkrtz + dword bpermute): 8 shuffles + 4 selects per p instead of
// 16 shuffles + 8 selects + 8 cvts.
__global__ __launch_bounds__(512, 4)
void layer_attn(const half_t* __restrict__ xsrc, const float* __restrict__ stats0,
                const float* __restrict__ g0, const float* __restrict__ be0,
                const half_t* __restrict__ wqkv, const float* __restrict__ bqkv,
                const half_t* __restrict__ wo, const float* __restrict__ bo,
                half_t* __restrict__ y16, float* __restrict__ stats)
{
    __shared__ alignas(16) half_t regA[14336];   // 28,672 B
    __shared__ alignas(16) half_t regB[26624];   // 53,248 B
    half_t* sX = regA;                 // [4][112*32]
    half_t* sQ = regA;                 // [8][112*16]  (overlay, post-phase-2)
    half_t* sK = regB;                 // [8][104*16]  (live through phase 3)
    half_t* sV = regB + 13312;         // [8][104*16]
    half_t* sO = regB + 13312;         // [104][128]   (overlay after vt hoist)
    float* sBN2 = (float*)regB;        // 1 KB table (phase 1 only)

    const int b   = blockIdx.x;
    const int tid = threadIdx.x;
    const int wave = tid >> 6, lane = tid & 63;
    const int quad = lane >> 4, l16 = lane & 15;
    const float invN = 1.0f / (float)TROWS;

    // ---- phase 1: BN2 table (if prev layer), then stage x' tile
    if (stats0) {
        if (tid < 128) {
            float mean = stats0[tid] * invN;
            float var  = stats0[128 + tid] * invN - mean * mean;
            float scl  = g0[tid] * rsqrtf(var + 1e-5f);
            sBN2[tid]       = scl;
            sBN2[128 + tid] = be0[tid] - mean * scl;
        }
        __syncthreads();
    }
    if (tid < 448) {
        int row = tid >> 2, q = tid & 3;
        int qs = ((q ^ (row >> 1)) & 3) << 3;
        h8 out[4];
        if (row < NCITY) {
            const half_t* src = xsrc + ((size_t)b * NCITY + row) * 128 + q * 8;
            #pragma unroll
            for (int kc = 0; kc < 4; ++kc) {
                h8 v = *(const h8*)(src + kc * 32);
                if (stats0) {
                    #pragma unroll
                    for (int r = 0; r < 8; ++r) {
                        int c = kc * 32 + q * 8 + r;
                        v[r] = (half_t)((float)v[r] * sBN2[c] + sBN2[128 + c]);
                    }
                }
                out[kc] = v;
            }
        } else {
            h8 z = {};
            out[0] = z; out[1] = z; out[2] = z; out[3] = z;
        }
        #pragma unroll
        for (int kc = 0; kc < 4; ++kc)
            *(h8*)(&sX[kc * 3584 + row * 32 + qs]) = out[kc];
    }
    __syncthreads();

    // ---- phase 2: per-wave QKV for head `wave`, 3 register-lean passes
    const int hn  = wave * 16 + l16;         // output column 0..127
    const int nsw = (hn >> 1) & 3;
    half_t* dstK = sK + wave * 1664;
    half_t* dstV = sV + wave * 1664;

    // K pass
    {
        h8 bw[4];
        const half_t* wrow = wqkv + 16384 + (size_t)hn * 128;
        #pragma unroll
        for (int kc = 0; kc < 4; ++kc)
            bw[kc] = *(const h8*)(wrow + kc * 32 + (((quad ^ nsw) & 3) << 3));
        float bb = bqkv[128 + hn];
        #pragma unroll
        for (int mi = 0; mi < 7; ++mi) {
            f32x4 a = {};
            #pragma unroll
            for (int kc = 0; kc < 4; ++kc) {
                int r = mi * 16 + l16;
                h8 af = *(const h8*)(&sX[kc * 3584 + r * 32 + (((quad ^ (r >> 1)) & 3) << 3)]);
                a = __builtin_amdgcn_mfma_f32_16x16x32_f16(af, bw[kc], a, 0, 0, 0);
            }
            #pragma unroll
            for (int r = 0; r < 4; ++r) {
                int tok = mi * 16 + quad * 4 + r;
                if (tok < 104)
                    dstK[tok * 16 + (l16 ^ (((tok >> 2) & 1) << 3))] = (half_t)(a[r] + bb);
            }
        }
    }
    __builtin_amdgcn_sched_barrier(0);
    // V pass
    {
        h8 bw[4];
        const half_t* wrow = wqkv + 2 * 16384 + (size_t)hn * 128;
        #pragma unroll
        for (int kc = 0; kc < 4; ++kc)
            bw[kc] = *(const h8*)(wrow + kc * 32 + (((quad ^ nsw) & 3) << 3));
        float bb = bqkv[256 + hn];
        #pragma unroll
        for (int mi = 0; mi < 7; ++mi) {
            f32x4 a = {};
            #pragma unroll
            for (int kc = 0; kc < 4; ++kc) {
                int r = mi * 16 + l16;
                h8 af = *(const h8*)(&sX[kc * 3584 + r * 32 + (((quad ^ (r >> 1)) & 3) << 3)]);
                a = __builtin_amdgcn_mfma_f32_16x16x32_f16(af, bw[kc], a, 0, 0, 0);
            }
            #pragma unroll
            for (int r = 0; r < 4; ++r) {
                int tok = mi * 16 + quad * 4 + r;
                if (tok < 104)
                    dstV[tok * 16 + (l16 ^ (((tok >> 2) & 1) << 3))] = (half_t)(a[r] + bb);
            }
        }
    }
    __builtin_amdgcn_sched_barrier(0);
    // Q pass -> packed regs (sQ overlay not writable until barrier)
    h4 qh[7];
    {
        h8 bw[4];
        const half_t* wrow = wqkv + (size_t)hn * 128;
        #pragma unroll
        for (int kc = 0; kc < 4; ++kc)
            bw[kc] = *(const h8*)(wrow + kc * 32 + (((quad ^ nsw) & 3) << 3));
        float bb = bqkv[hn];
        #pragma unroll
        for (int mi = 0; mi < 7; ++mi) {
            f32x4 a = {};
            #pragma unroll
            for (int kc = 0; kc < 4; ++kc) {
                int r = mi * 16 + l16;
                h8 af = *(const h8*)(&sX[kc * 3584 + r * 32 + (((quad ^ (r >> 1)) & 3) << 3)]);
                a = __builtin_amdgcn_mfma_f32_16x16x32_f16(af, bw[kc], a, 0, 0, 0);
            }
            #pragma unroll
            for (int r = 0; r < 4; ++r)
                qh[mi][r] = (half_t)(a[r] + bb);
        }
    }
    __syncthreads();   // all sX reads + K/V writes done -> sQ overlay safe, K/V visible

    // write Q into region A (wave-private chunk of old sX)
    {
        half_t* dstQ = sQ + wave * 1792;
        #pragma unroll
        for (int mi = 0; mi < 7; ++mi)
            #pragma unroll
            for (int r = 0; r < 4; ++r) {
                int tok = mi * 16 + quad * 4 + r;
                int dsw = l16 ^ (((tok >> 2) & 1) << 3);
                dstQ[tok * 16 + dsw] = qh[mi][r];
            }
    }
    const half_t* qb = sQ + wave * 1792;
    const half_t* kb = sK + wave * 1664;
    const half_t* vb = sV + wave * 1664;
    const int kflip = (l16 >> 2) & 1;

    // hoist V fragments only (16 VGPRs); kf re-read per tile in phase 3
    h8 vt[4];
    #pragma unroll
    for (int p = 0; p < 4; ++p)
        #pragma unroll
        for (int jj = 0; jj < 8; ++jj) {
            int tok = p * 32 + quad * 8 + jj;
            int tokc = tok < 104 ? tok : 103;   // clamped; P=0 for tok>=101
            vt[p][jj] = vb[tokc * 16 + (l16 ^ (((jj >> 2) & 1) << 3))];
        }
    __syncthreads();   // all V reads + Q writes done -> sO (over sV) safe

    // ---- phase 3: attention (per-wave private; K re-read from LDS per tile)
    const int s0 = (((quad & 1) * 2)    ) * 16 + l16;
    const int s1 = (((quad & 1) * 2) + 1) * 16 + l16;
    const bool hi2 = (quad >> 1) != 0;
    const int ocol = hn;                       // this wave's output column

    for (int it = 0; it < 7; ++it) {
        h8 qf = {};
        if (quad < 2)
            qf = *(const h8*)(qb + (it * 16 + l16) * 16 + ((quad ^ kflip) << 3));

        f32x4 S[7];
        #pragma unroll
        for (int jt = 0; jt < 7; ++jt) {
            h8 kf = {};
            if (quad < 2) {
                int rowk = jt * 16 + l16;
                rowk = rowk < 104 ? rowk : 103;   // clamped; masked downstream
                kf = *(const h8*)(kb + rowk * 16 + ((quad ^ kflip) << 3));
            }
            f32x4 a = {};
            a = __builtin_amdgcn_mfma_f32_16x16x32_f16(kf, qf, a, 0, 0, 0);
            S[jt] = a;
        }
        float m = -1e30f;
        #pragma unroll
        for (int jt = 0; jt < 7; ++jt)
            #pragma unroll
            for (int r = 0; r < 4; ++r) {
                int jg = jt * 16 + quad * 4 + r;
                float sv = (jg < NCITY) ? S[jt][r] * 0.25f : -1e30f;
                S[jt][r] = sv;
                m = fmaxf(m, sv);
            }
        m = fmaxf(m, __shfl_xor(m, 16));
        m = fmaxf(m, __shfl_xor(m, 32));
        float sum = 0.0f;
        #pragma unroll
        for (int jt = 0; jt < 7; ++jt)
            #pragma unroll
            for (int r = 0; r < 4; ++r) {
                float e = __expf(S[jt][r] - m);
                S[jt][r] = e;
                sum += e;
            }
        sum += __shfl_xor(sum, 16);
        sum += __shfl_xor(sum, 32);
        float inv = 1.0f / sum;
        #pragma unroll
        for (int jt = 0; jt < 7; ++jt)
            #pragma unroll
            for (int r = 0; r < 4; ++r) S[jt][r] *= inv;

        // pre-pack normalized P rows to f16 pairs: pk0 = (r0,r1), pk1 = (r2,r3)
        unsigned pk0[7], pk1[7];
        #pragma unroll
        for (int jt = 0; jt < 7; ++jt) {
            pk0[jt] = __builtin_bit_cast(unsigned, __builtin_amdgcn_cvt_pkrtz(S[jt][0], S[jt][1]));
            pk1[jt] = __builtin_bit_cast(unsigned, __builtin_amdgcn_cvt_pkrtz(S[jt][2], S[jt][3]));
        }

        f32x4 O = {};
        #pragma unroll
        for (int p = 0; p < 4; ++p) {
            // packed-dword broadcast: ph[2i..2i+1] dwords via s0/s1 + hi2 jt-select
            unsigned lo0 = (unsigned)__shfl((int)pk0[2 * p],     s0);
            unsigned lo1 = (unsigned)__shfl((int)pk0[2 * p + 1], s0);
            unsigned m10 = (unsigned)__shfl((int)pk1[2 * p],     s0);
            unsigned m11 = (unsigned)__shfl((int)pk1[2 * p + 1], s0);
            unsigned h00 = (unsigned)__shfl((int)pk0[2 * p],     s1);
            unsigned h01 = (unsigned)__shfl((int)pk0[2 * p + 1], s1);
            unsigned h10 = (unsigned)__shfl((int)pk1[2 * p],     s1);
            unsigned h11 = (unsigned)__shfl((int)pk1[2 * p + 1], s1);
            u32x4 pd;
            pd[0] = hi2 ? lo1 : lo0;   // ph[0],ph[1]
            pd[1] = hi2 ? m11 : m10;   // ph[2],ph[3]
            pd[2] = hi2 ? h01 : h00;   // ph[4],ph[5]
            pd[3] = hi2 ? h11 : h10;   // ph[6],ph[7]
            h8 ph = __builtin_bit_cast(h8, pd);
            O = __builtin_amdgcn_mfma_f32_16x16x32_f16(ph, vt[p], O, 0, 0, 0);
        }
        // O -> sO[104][128], granule swizzle g' = g ^ (q&7) -> conflict-free
        #pragma unroll
        for (int r = 0; r < 4; ++r) {
            int q = it * 16 + quad * 4 + r;
            if (q < 104) {
                int g = (ocol >> 3) ^ (q & 7);
                sO[q * 128 + g * 8 + (ocol & 7)] = (half_t)O[r];
            }
        }
    }
    __syncthreads();

    // ---- phase 4: O-proj (wave w owns cols w*16..+15), residual(+BN2), BN1 stats
    h8 bfr2[4];
    {
        const half_t* wrow = wo + (size_t)ocol * 128;
        const int nsw2 = (ocol >> 1) & 3;
        #pragma unroll
        for (int kc = 0; kc < 4; ++kc)
            bfr2[kc] = *(const h8*)(wrow + kc * 32 + (((quad ^ nsw2) & 3) << 3));
    }
    f32x4 acc[7];
    #pragma unroll
    for (int mi = 0; mi < 7; ++mi) {
        acc[mi] = (f32x4){};
        int row = mi * 16 + l16;
        int rc = row < 104 ? row : 103;   // rows>=104 garbage -> masked at store
        #pragma unroll
        for (int kc = 0; kc < 4; ++kc) {
            int g = (kc * 4 + quad) ^ (rc & 7);
            h8 af = *(const h8*)(&sO[rc * 128 + g * 8]);
            acc[mi] = __builtin_amdgcn_mfma_f32_16x16x32_f16(af, bfr2[kc], acc[mi], 0, 0, 0);
        }
    }
    float sclo = 1.0f, shfo = 0.0f;
    if (stats0) {
        float mean = stats0[ocol] * invN;
        float var  = stats0[128 + ocol] * invN - mean * mean;
        sclo = g0[ocol] * rsqrtf(var + 1e-5f);
        shfo = be0[ocol] - mean * sclo;
    }
    float bvv = bo[ocol];
    float s = 0.0f, ss = 0.0f;
    #pragma unroll
    for (int mi = 0; mi < 7; ++mi) {
        #pragma unroll
        for (int r = 0; r < 4; ++r) {
            int q = mi * 16 + quad * 4 + r;
            if (q < NCITY) {
                size_t grow = (size_t)b * NCITY + q;
                float xv = (float)xsrc[grow * 128 + ocol] * sclo + shfo;
                float o = acc[mi][r] + bvv + xv;
                y16[grow * 128 + ocol] = (half_t)o;
                s += o; ss += o * o;
            }
        }
    }
    s  += __shfl_xor(s, 16);  s  += __shfl_xor(s, 32);
    ss += __shfl_xor(ss, 16); ss += __shfl_xor(ss, 32);
    if (quad == 0) {
        atomicAdd(&stats[ocol], s);
        atomicAdd(&stats[128 + ocol], ss);
    }
}

// ---------------- fused BN1 + FF1(ReLU) + FF2 ----------------
// 512 threads / 8 waves, 80 KB LDS -> 2 blocks/CU.
// Weights reg-staged: next round's loads issued under compute.
// Epilogue residual x' read back from sX (LDS) -- no y16 re-read.
__global__ __launch_bounds__(512, 4)
void ff_fused(half_t* __restrict__ y16, const float* __restrict__ st1,
              const float* __restrict__ g1, const float* __restrict__ be1,
              const half_t* __restrict__ w1, const half_t* __restrict__ w2,
              const float* __restrict__ bf1, const float* __restrict__ bf2,
              float* __restrict__ stats)
{
    __shared__ alignas(16) half_t sX[4][128 * 32];   // 32 KB  x' tile
    __shared__ alignas(16) half_t sW1f[8192];        // 16 KB  wf1 chunk image (flat)
    __shared__ alignas(16) half_t sW2f[8192];        // 16 KB  wf2 chunk image (flat)
    __shared__ alignas(16) half_t sH[2][128 * 32];   // 16 KB  relu chunk

    const int tid  = threadIdx.x;
    const int wave = tid >> 6, lane = tid & 63;
    const int quad = lane >> 4, l16 = lane & 15;
    const int m0 = blockIdx.x * 128;
    const int wr = wave >> 1;          // 0..3: 32-row group
    const int wc = wave & 1;           // col group

    const float invN = 1.0f / (float)TROWS;
    const int so = wave * 512 + lane * 8;    // identity global<->LDS offset

    // prologue: round-0 weight regs
    h8 rw1a = *(const h8*)(w1 + so);
    h8 rw1b = *(const h8*)(w1 + so + 4096);
    h8 rw2a = *(const h8*)(w2 + so);
    h8 rw2b = *(const h8*)(w2 + so + 4096);

    // BN1 scale/shift table (1 KB, overlaid in sW1f; dead after sX stage)
    float* sBN = (float*)&sW1f[0];
    if (tid < 128) {
        float mean = st1[tid] * invN;
        float var  = st1[128 + tid] * invN - mean * mean;
        float scl  = g1[tid] * rsqrtf(var + 1e-5f);
        sBN[tid]       = scl;
        sBN[128 + tid] = be1[tid] - mean * scl;
    }
    __syncthreads();

    // stage x' = BN1(y16) -> sX (swizzled)
    {
        const int row = tid >> 2;            // 0..127
        const int q   = tid & 3;
        const int qs  = ((q ^ (row >> 1)) & 3) << 3;
        const half_t* src = y16 + (size_t)(m0 + row) * 128 + q * 8;
        #pragma unroll
        for (int kc = 0; kc < 4; ++kc) {
            h8 v = *(const h8*)(src + kc * 32);
            h8 xv;
            #pragma unroll
            for (int r = 0; r < 8; ++r) {
                int c = kc * 32 + q * 8 + r;
                xv[r] = (half_t)((float)v[r] * sBN[c] + sBN[128 + c]);
            }
            *(h8*)(&sX[kc][row * 32 + qs]) = xv;
        }
    }

    f32x4 acc2[2][4] = {};

    for (int j = 0; j < 8; ++j) {
        // b1: FF2(j-1) done reading sW/sH; sX/sBN writes visible (j=0)
        asm volatile("s_waitcnt lgkmcnt(0)" ::: "memory");
        __builtin_amdgcn_s_barrier();
        __builtin_amdgcn_sched_barrier(0);
        // write W(j) from regs (compiler inserts the per-thread vmcnt waits)
        *(h8*)(&sW1f[so])        = rw1a;
        *(h8*)(&sW1f[so + 4096]) = rw1b;
        *(h8*)(&sW2f[so])        = rw2a;
        *(h8*)(&sW2f[so + 4096]) = rw2b;
        asm volatile("s_waitcnt lgkmcnt(0)" ::: "memory");
        __builtin_amdgcn_s_barrier();
        __builtin_amdgcn_sched_barrier(0);
        if (j < 7) {   // issue next round's loads; they fly under FF1+FF2
            const half_t* w1n = w1 + (size_t)(j + 1) * 8192;
            const half_t* w2n = w2 + (size_t)(j + 1) * 8192;
            rw1a = *(const h8*)(w1n + so);
            rw1b = *(const h8*)(w1n + so + 4096);
            rw2a = *(const h8*)(w2n + so);
            rw2b = *(const h8*)(w2n + so + 4096);
        }

        // FF1: wave tile 32x32 of 128x64 chunk
        f32x4 acc1[2][2] = {};
        #pragma unroll
        for (int kc = 0; kc < 4; ++kc) {
            h8 af[2], bf[2];
            #pragma unroll
            for (int mi = 0; mi < 2; ++mi) {
                int r = wr * 32 + mi * 16 + l16;
                af[mi] = *(const h8*)(&sX[kc][r * 32 + (((quad ^ (r >> 1)) & 3) << 3)]);
            }
            #pragma unroll
            for (int ni = 0; ni < 2; ++ni) {
                int n = wc * 32 + ni * 16 + l16;
                bf[ni] = *(const h8*)(&sW1f[kc * 2048 + n * 32 + (((quad ^ (n >> 1)) & 3) << 3)]);
            }
            #pragma unroll
            for (int mi = 0; mi < 2; ++mi)
            #pragma unroll
            for (int ni = 0; ni < 2; ++ni)
                acc1[mi][ni] = __builtin_amdgcn_mfma_f32_16x16x32_f16(af[mi], bf[ni], acc1[mi][ni], 0, 0, 0);
        }
        // bias + ReLU -> sH (swizzled scalar writes)
        #pragma unroll
        for (int ni = 0; ni < 2; ++ni) {
            int c = wc * 32 + ni * 16 + l16;       // 0..63
            float bvv = bf1[j * 64 + c];
            int kc2 = c >> 5, c5 = c & 31;
            #pragma unroll
            for (int mi = 0; mi < 2; ++mi)
            #pragma unroll
            for (int r = 0; r < 4; ++r) {
                int row = wr * 32 + mi * 16 + quad * 4 + r;
                float v = acc1[mi][ni][r] + bvv;
                v = v > 0.0f ? v : 0.0f;
                int hsw = (c5 & 7) | ((((c5 >> 3) ^ (row >> 1)) & 3) << 3);
                sH[kc2][row * 32 + hsw] = (half_t)v;
            }
        }
        asm volatile("s_waitcnt lgkmcnt(0)" ::: "memory");
        __builtin_amdgcn_s_barrier();
        __builtin_amdgcn_sched_barrier(0);

        // FF2 partial: wave tile 32x64, K-slice 64
        #pragma unroll
        for (int kc = 0; kc < 2; ++kc) {
            h8 af[2], bf[4];
            #pragma unroll
            for (int mi = 0; mi < 2; ++mi) {
                int r = wr * 32 + mi * 16 + l16;
                af[mi] = *(const h8*)(&sH[kc][r * 32 + (((quad ^ (r >> 1)) & 3) << 3)]);
            }
            #pragma unroll
            for (int ni = 0; ni < 4; ++ni) {
                int n = wc * 64 + ni * 16 + l16;
                bf[ni] = *(const h8*)(&sW2f[kc * 4096 + n * 32 + (((quad ^ (n >> 1)) & 3) << 3)]);
            }
            #pragma unroll
            for (int mi = 0; mi < 2; ++mi)
            #pragma unroll
            for (int ni = 0; ni < 4; ++ni)
                acc2[mi][ni] = __builtin_amdgcn_mfma_f32_16x16x32_f16(af[mi], bf[ni], acc2[mi][ni], 0, 0, 0);
        }
    }

    // epilogue: y2 = acc2 + bf2 + x' (x' read from sX), BN2 stats
    __syncthreads();                       // sH reads done -> reuse as reduction scratch
    float* red = (float*)&sH[0][0];        // [2][512] floats (s, ss)

    #pragma unroll
    for (int ni = 0; ni < 4; ++ni) {
        int col = wc * 64 + ni * 16 + l16;
        float bvv = bf2[col];
        int kc = col >> 5, c5 = col & 31;
        float s = 0.0f, ss = 0.0f;
        #pragma unroll
        for (int mi = 0; mi < 2; ++mi) {
            #pragma unroll
            for (int r = 0; r < 4; ++r) {
                int rowl = wr * 32 + mi * 16 + quad * 4 + r;
                int hsw = (c5 & 7) | ((((c5 >> 3) ^ (rowl >> 1)) & 3) << 3);
                float xv = (float)sX[kc][rowl * 32 + hsw];
                float o = acc2[mi][ni][r] + bvv + xv;
                y16[(size_t)(m0 + rowl) * 128 + col] = (half_t)o;
                s += o; ss += o * o;
            }
        }
        s  += __shfl_xor(s, 16);  s  += __shfl_xor(s, 32);
        ss += __shfl_xor(ss, 16); ss += __shfl_xor(ss, 32);
        if (quad == 0) {
            red[wave * 64 + ni * 16 + l16]       = s;
            red[512 + wave * 64 + ni * 16 + l16] = ss;
        }
    }
    __syncthreads();
    if (tid < 256) {
        int a   = tid >> 7;          // 0 = s, 1 = ss
        int col = tid & 127;
        int wcc = col >> 6, nii = (col >> 4) & 3, lx = col & 15;
        float t = 0.0f;
        #pragma unroll
        for (int w = 0; w < 4; ++w)
            t += red[a * 512 + (w * 2 + wcc) * 64 + nii * 16 + lx];
        atomicAdd(&stats[a * 128 + col], t);
    }
}

// ---------------- BatchNorm apply (final layer only: fp32 out) ----------------
__global__ __launch_bounds__(256)
void bn_apply(const h8* __restrict__ y, const float* __restrict__ stats,
              const float* __restrict__ g, const float* __restrict__ be,
              float* __restrict__ dst32)
{
    __shared__ float sh[256];
    const int tid = threadIdx.x;
    if (tid < 128) {
        const float invN = 1.0f / (float)TROWS;
        float mean = stats[tid] * invN;
        float var  = stats[128 + tid] * invN - mean * mean;
        float inv  = rsqrtf(var + 1e-5f);
        float scl  = g[tid] * inv;
        sh[tid]       = scl;
        sh[128 + tid] = be[tid] - mean * scl;
    }
    __syncthreads();

    int gid = blockIdx.x * 256 + tid;   // over TROWS*16 (8 ch each)
    int c = (gid & 15) * 8;
    h8 v = y[gid];
    float o[8];
    #pragma unroll
    for (int r = 0; r < 8; ++r)
        o[r] = (float)v[r] * sh[c + r] + sh[128 + c + r];
    f32x4 lo = { o[0], o[1], o[2], o[3] };
    f32x4 hi = { o[4], o[5], o[6], o[7] };
    ((f32x4*)dst32)[gid * 2]     = lo;
    ((f32x4*)dst32)[gid * 2 + 1] = hi;
}

// ---------------- launch ----------------
extern "C" void kernel_launch(void* const* d_in, const int* in_sizes, int n_in,
                              void* d_out, int out_size, void* d_ws, size_t ws_size,
                              hipStream_t stream)
{
    const float* s    = (const float*)d_in[0];
    const int*   dd   = (const int*)d_in[1];
    const float* e_w  = (const float*)d_in[2];
    const float* e_b  = (const float*)d_in[3];
    const float* ep_w = (const float*)d_in[4];
    const float* ep_b = (const float*)d_in[5];
    const float* Wq   = (const float*)d_in[6];
    const float* bq   = (const float*)d_in[7];
    const float* Wk   = (const float*)d_in[8];
    const float* bk   = (const float*)d_in[9];
    const float* Wv   = (const float*)d_in[10];
    const float* bv   = (const float*)d_in[11];
    const float* Wo   = (const float*)d_in[12];
    const float* bo   = (const float*)d_in[13];
    const float* Wf1  = (const float*)d_in[14];
    const float* bf1  = (const float*)d_in[15];
    const float* Wf2  = (const float*)d_in[16];
    const float* bf2  = (const float*)d_in[17];
    const float* g1   = (const float*)d_in[18];
    const float* be1  = (const float*)d_in[19];
    const float* g2   = (const float*)d_in[20];
    const float* be2  = (const float*)d_in[21];

    char* ws = (char*)d_ws;
    size_t off = 0;
    auto alloc = [&](size_t bytes) -> void* {
        void* p = ws + off;
        off += (bytes + 255) & ~(size_t)255;
        return p;
    };
    half_t* y16   = (half_t*)alloc((size_t)TROWS * 128 * 2);
    half_t* xh    = (half_t*)alloc((size_t)TROWS * 128 * 2);
    half_t* wqkv  = (half_t*)alloc((size_t)3 * 384 * 128 * 2);
    half_t* wo    = (half_t*)alloc((size_t)3 * 128 * 128 * 2);
    half_t* wf1   = (half_t*)alloc((size_t)3 * 512 * 128 * 2);
    half_t* wf2   = (half_t*)alloc((size_t)3 * 128 * 512 * 2);
    float*  bqkv  = (float*) alloc((size_t)3 * 384 * 4);
    float*  stats = (float*) alloc(6 * 256 * 4);

    dim3 blk(256);

    hipMemsetAsync(stats, 0, 6 * 256 * 4, stream);

    prep_kernel<<<dim3(768, 7), blk, 0, stream>>>(Wq, Wk, Wv, Wo, Wf1, Wf2, bq, bk, bv,
                                                  wqkv, wo, wf1, wf2, bqkv);

    embed_kernel<<<dim3(TROWS * 128 / 256), blk, 0, stream>>>(s, dd, e_w, e_b, ep_w, ep_b, xh);

    for (int l = 0; l < 3; ++l) {
        float* st1 = stats + (size_t)(l * 2) * 256;
        float* st2 = stats + (size_t)(l * 2 + 1) * 256;
        const float* st0 = (l == 0) ? nullptr : stats + (size_t)((l - 1) * 2 + 1) * 256;
        const half_t* xsrc = (l == 0) ? xh : y16;
        // [BN2 prev] + QKV + attention + O-proj + residual + BN1 stats -> y16
        layer_attn<<<dim3(BATCH), dim3(512), 0, stream>>>(xsrc, st0,
                                                          g2 + (l ? (l - 1) * 128 : 0),
                                                          be2 + (l ? (l - 1) * 128 : 0),
                                                          wqkv + (size_t)l * 49152,
                                                          bqkv + l * 384,
                                                          wo + (size_t)l * 16384,
                                                          bo + l * 128, y16, st1);
        // fused BN1-apply + FF1 + FF2 + residual + BN2 stats (in-place y16)
        ff_fused<<<dim3(404), dim3(512), 0, stream>>>(y16, st1, g1 + l * 128, be1 + l * 128,
                                                      wf1 + (size_t)l * 65536, wf2 + (size_t)l * 65536,
                                                      bf1 + l * 512, bf2 + l * 128, st2);
    }
    // final BN2 apply -> fp32 output
    bn_apply<<<dim3(TROWS * 16 / 256), blk, 0, stream>>>((const h8*)y16, stats + 5 * 256,
                                                         g2 + 2 * 128, be2 + 2 * 128,
                                                         (float*)d_out);
}